// Round 2
// baseline (375.912 us; speedup 1.0000x reference)
//
#include <hip/hip_runtime.h>
#include <hip/hip_bf16.h>

typedef unsigned short u16;
typedef __attribute__((ext_vector_type(8))) short bf16x8;
typedef __attribute__((ext_vector_type(8))) unsigned short u16x8;
typedef __attribute__((ext_vector_type(4))) float f32x4;

#define NBT 64
#define SEQ 197
#define CDIM 768
#define NH 12
#define HD 64
#define MVALID (NBT * SEQ)       // 12608
#define MPAD 12672               // 99 * 128
#define HADP 192
#define HPAD 256
#define QKVSZ (NBT * NH * SEQ * HD)  // 9682944 elements

__device__ __forceinline__ u16 f2b(float f) {
    __hip_bfloat16 h = __float2bfloat16(f);
    return __builtin_bit_cast(u16, h);
}

#define GLL16(gp, lp) __builtin_amdgcn_global_load_lds( \
    (__attribute__((address_space(1))) void*)(gp),      \
    (__attribute__((address_space(3))) void*)(lp), 16, 0, 0)

// ---------------------------------------------------------------- cast x -> bf16, pad rows to MPAD with zeros
__global__ __launch_bounds__(256) void cast_x_kernel(const float* __restrict__ x, u16* __restrict__ xb) {
    long i = ((long)blockIdx.x * 256 + threadIdx.x) * 8;
    u16x8 r;
    if (i < (long)MVALID * CDIM) {
        const float4* p = (const float4*)(x + i);
        float4 a = p[0], b = p[1];
        r[0] = f2b(a.x); r[1] = f2b(a.y); r[2] = f2b(a.z); r[3] = f2b(a.w);
        r[4] = f2b(b.x); r[5] = f2b(b.y); r[6] = f2b(b.z); r[7] = f2b(b.w);
    } else {
#pragma unroll
        for (int j = 0; j < 8; ++j) r[j] = 0;
    }
    *(u16x8*)(xb + i) = r;
}

// ---------------------------------------------------------------- fp32 [K][N] -> bf16 [NP][KP] transpose+cast, zero pad
// grid = (KP/64, NP/64)
__global__ __launch_bounds__(256) void transpose_cast_kernel(
    const float* __restrict__ in, u16* __restrict__ out, int K, int N, int KP) {
    __shared__ float tile[64][65];
    int k0 = blockIdx.x * 64;
    int n0 = blockIdx.y * 64;
    int c  = threadIdx.x & 63;
    int r0 = threadIdx.x >> 6;
#pragma unroll
    for (int rr = r0; rr < 64; rr += 4) {
        int k = k0 + rr, n = n0 + c;
        tile[rr][c] = (k < K && n < N) ? in[(long)k * N + n] : 0.f;
    }
    __syncthreads();
#pragma unroll
    for (int rr = r0; rr < 64; rr += 4) {
        out[(long)(n0 + rr) * KP + k0 + c] = f2b(tile[c][rr]);
    }
}

// ---------------------------------------------------------------- GEMM: C[M,N] = A[M,K] * Bt[N,K]^T (+epilogue)
// 128x128 tile, BK=64, 256 threads (4 waves 2x2), dbuf LDS via global_load_lds w16.
// MODE 0: h = acc + b1(pad0)            -> ob [MPAD][HPAD] bf16
// MODE 1: xa = acc + b2 + x (residual)  -> ob [MPAD][CDIM] bf16 (0 for pad rows)
// MODE 2: qkv scatter                   -> ob [3][NBT][NH][SEQ][HD] bf16
// MODE 3: out = acc + proj_b            -> of [MVALID][CDIM] fp32
template <int MODE>
__global__ __launch_bounds__(256, 2) void gemm_kernel(
    const u16* __restrict__ A, const u16* __restrict__ Bt,
    const float* __restrict__ bias, const float* __restrict__ resid,
    u16* __restrict__ ob, float* __restrict__ of, int K) {
    __shared__ __align__(16) u16 As[2][128 * 64];
    __shared__ __align__(16) u16 Bs[2][128 * 64];
    const int tid  = threadIdx.x;
    const int lane = tid & 63;
    const int w    = tid >> 6;
    const int wm   = w >> 1, wn = w & 1;
    const long m0  = (long)blockIdx.x * 128;
    const long n0  = (long)blockIdx.y * 128;

    const int rA = lane >> 3;
    const int cA = (lane & 7) * 8;

    const u16* ga[4];
    const u16* gb[4];
#pragma unroll
    for (int ii = 0; ii < 4; ++ii) {
        int i = w * 4 + ii;
        ga[ii] = A  + (m0 + i * 8 + rA) * K + cA;
        gb[ii] = Bt + (n0 + i * 8 + rA) * K + cA;
    }
#pragma unroll
    for (int ii = 0; ii < 4; ++ii) {
        int i = w * 4 + ii;
        GLL16(ga[ii], &As[0][i * 512]);
        GLL16(gb[ii], &Bs[0][i * 512]);
    }

    int aoff[4], boff[4];
#pragma unroll
    for (int t = 0; t < 4; ++t) {
        aoff[t] = (wm * 64 + t * 16 + (lane & 15)) * 64 + (lane >> 4) * 8;
        boff[t] = (wn * 64 + t * 16 + (lane & 15)) * 64 + (lane >> 4) * 8;
    }

    f32x4 acc[4][4] = {};
    const int kSteps = K >> 6;
    __syncthreads();
    int buf = 0;
    for (int kt = 0; kt < kSteps; ++kt) {
        if (kt + 1 < kSteps) {
#pragma unroll
            for (int ii = 0; ii < 4; ++ii) {
                int i = w * 4 + ii;
                GLL16(ga[ii] + (kt + 1) * 64, &As[buf ^ 1][i * 512]);
                GLL16(gb[ii] + (kt + 1) * 64, &Bs[buf ^ 1][i * 512]);
            }
        }
#pragma unroll
        for (int kc = 0; kc < 2; ++kc) {
            bf16x8 af[4], bg[4];
#pragma unroll
            for (int t = 0; t < 4; ++t) af[t] = *(const bf16x8*)&As[buf][aoff[t] + kc * 32];
#pragma unroll
            for (int t = 0; t < 4; ++t) bg[t] = *(const bf16x8*)&Bs[buf][boff[t] + kc * 32];
#pragma unroll
            for (int mi = 0; mi < 4; ++mi)
#pragma unroll
                for (int ni = 0; ni < 4; ++ni)
                    acc[mi][ni] = __builtin_amdgcn_mfma_f32_16x16x32_bf16(af[mi], bg[ni], acc[mi][ni], 0, 0, 0);
        }
        __syncthreads();
        buf ^= 1;
    }

    // epilogue: D row = (lane>>4)*4 + r, col = lane&15 within each 16x16 frag
    const int rb = (lane >> 4) * 4;
    const int cl = lane & 15;
#pragma unroll
    for (int mi = 0; mi < 4; ++mi) {
#pragma unroll
        for (int r = 0; r < 4; ++r) {
            long m = m0 + wm * 64 + mi * 16 + rb + r;
#pragma unroll
            for (int ni = 0; ni < 4; ++ni) {
                long n = n0 + wn * 64 + ni * 16 + cl;
                float v = acc[mi][ni][r];
                if constexpr (MODE == 0) {
                    float bv = (n < HADP) ? bias[n] : 0.f;
                    ob[m * HPAD + n] = f2b(v + bv);
                } else if constexpr (MODE == 1) {
                    float val = 0.f;
                    if (m < MVALID) val = v + bias[n] + resid[m * CDIM + n];
                    ob[m * CDIM + n] = f2b(val);
                } else if constexpr (MODE == 2) {
                    if (m < MVALID) {
                        int mm = (int)m;
                        int bb = mm / SEQ;
                        int t  = mm - bb * SEQ;
                        int nn = (int)n;
                        int which = nn / CDIM;
                        int c  = nn - which * CDIM;
                        int hh = c >> 6, d = c & 63;
                        ob[(long)which * QKVSZ + ((long)(bb * NH + hh) * SEQ + t) * HD + d] = f2b(v + bias[nn]);
                    }
                } else {
                    if (m < MVALID) of[m * CDIM + n] = v + bias[n];
                }
            }
        }
    }
}

// ---------------------------------------------------------------- attention: one block per (b,h), 4 waves
// Head reallocation handled by reading K/V from bsrc (shifted frame).
__global__ __launch_bounds__(256, 2) void attn_kernel(
    const u16* __restrict__ qb, const u16* __restrict__ kb, const u16* __restrict__ vb,
    u16* __restrict__ aout) {
    __shared__ __align__(16) u16 Vt[64 * 232];        // V transposed [d][token], padded
    __shared__ __align__(16) u16 P[4][16 * 232];      // per-wave P tile
    const int bid = blockIdx.x;
    const int b = bid / NH;
    const int h = bid - b * NH;
    const int f = b & 7;
    int fs = (h < 2) ? (f > 0 ? f - 1 : 0) : ((h < 4) ? (f < 7 ? f + 1 : 7) : f);
    const int bsrc = (b & ~7) + fs;
    const u16* Qp = qb + (long)(b    * NH + h) * SEQ * HD;
    const u16* Kp = kb + (long)(bsrc * NH + h) * SEQ * HD;
    const u16* Vp = vb + (long)(bsrc * NH + h) * SEQ * HD;

    const int tid  = threadIdx.x;
    const int lane = tid & 63;
    const int w    = tid >> 6;
    const int cl   = lane & 15;
    const int lg   = lane >> 4;

    {   // zero Vt and P (pad columns must be exactly 0)
        unsigned int* z1 = (unsigned int*)Vt;
        for (int i = tid; i < 64 * 232 / 2; i += 256) z1[i] = 0;
        unsigned int* z2 = (unsigned int*)&P[0][0];
        for (int i = tid; i < 4 * 16 * 232 / 2; i += 256) z2[i] = 0;
    }
    __syncthreads();
    for (int g = tid; g < SEQ * HD / 8; g += 256) {   // transpose-stage V
        int t  = g >> 3;
        int d0 = (g & 7) * 8;
        u16x8 v = *(const u16x8*)(Vp + g * 8);
#pragma unroll
        for (int j = 0; j < 8; ++j) Vt[(d0 + j) * 232 + t] = v[j];
    }
    __syncthreads();

    const f32x4 vzero = {0.f, 0.f, 0.f, 0.f};
    u16* Pw = &P[w][0];
    for (int rt = w; rt < 13; rt += 4) {
        int qrow = rt * 16 + cl; if (qrow > SEQ - 1) qrow = SEQ - 1;
        bf16x8 qf0 = *(const bf16x8*)(Qp + qrow * HD + lg * 8);
        bf16x8 qf1 = *(const bf16x8*)(Qp + qrow * HD + 32 + lg * 8);
        f32x4 s[13];
#pragma unroll
        for (int ct = 0; ct < 13; ++ct) s[ct] = vzero;
#pragma unroll
        for (int ct = 0; ct < 13; ++ct) {
            int krow = ct * 16 + cl; if (krow > SEQ - 1) krow = SEQ - 1;
            bf16x8 kf0 = *(const bf16x8*)(Kp + krow * HD + lg * 8);
            bf16x8 kf1 = *(const bf16x8*)(Kp + krow * HD + 32 + lg * 8);
            s[ct] = __builtin_amdgcn_mfma_f32_16x16x32_bf16(qf0, kf0, s[ct], 0, 0, 0);
            s[ct] = __builtin_amdgcn_mfma_f32_16x16x32_bf16(qf1, kf1, s[ct], 0, 0, 0);
        }
        // scale + mask + row max (rows lg*4..lg*4+3 live in 16-lane group lg)
        float rm[4] = {-1e30f, -1e30f, -1e30f, -1e30f};
#pragma unroll
        for (int ct = 0; ct < 13; ++ct) {
            bool valid = (ct * 16 + cl) <= SEQ - 1;
#pragma unroll
            for (int r = 0; r < 4; ++r) {
                float v = valid ? s[ct][r] * 0.125f : -1e30f;
                s[ct][r] = v;
                rm[r] = fmaxf(rm[r], v);
            }
        }
#pragma unroll
        for (int off = 1; off <= 8; off <<= 1)
#pragma unroll
            for (int r = 0; r < 4; ++r) rm[r] = fmaxf(rm[r], __shfl_xor(rm[r], off));
        float rs[4] = {0.f, 0.f, 0.f, 0.f};
#pragma unroll
        for (int ct = 0; ct < 13; ++ct)
#pragma unroll
            for (int r = 0; r < 4; ++r) {
                float p = __expf(s[ct][r] - rm[r]);
                s[ct][r] = p;
                rs[r] += p;
            }
#pragma unroll
        for (int off = 1; off <= 8; off <<= 1)
#pragma unroll
            for (int r = 0; r < 4; ++r) rs[r] += __shfl_xor(rs[r], off);
        float inv[4];
#pragma unroll
        for (int r = 0; r < 4; ++r) inv[r] = 1.f / rs[r];

        // write normalized P (bf16) to per-wave LDS; order DS ops around the cross-lane handoff
        asm volatile("s_waitcnt lgkmcnt(0)" ::: "memory");
#pragma unroll
        for (int ct = 0; ct < 13; ++ct)
#pragma unroll
            for (int r = 0; r < 4; ++r)
                Pw[(lg * 4 + r) * 232 + ct * 16 + cl] = f2b(s[ct][r] * inv[r]);
        asm volatile("s_waitcnt lgkmcnt(0)" ::: "memory");

        bf16x8 pf[7];
#pragma unroll
        for (int ks = 0; ks < 7; ++ks)
            pf[ks] = *(const bf16x8*)(Pw + cl * 232 + ks * 32 + lg * 8);
#pragma unroll
        for (int dt = 0; dt < 4; ++dt) {
            f32x4 o = vzero;
#pragma unroll
            for (int ks = 0; ks < 7; ++ks) {
                bf16x8 vf = *(const bf16x8*)(&Vt[(dt * 16 + cl) * 232 + ks * 32 + lg * 8]);
                o = __builtin_amdgcn_mfma_f32_16x16x32_bf16(pf[ks], vf, o, 0, 0, 0);
            }
#pragma unroll
            for (int r = 0; r < 4; ++r) {
                int m = rt * 16 + lg * 4 + r;
                if (m < SEQ)
                    aout[(long)(b * SEQ + m) * CDIM + h * HD + dt * 16 + cl] = f2b(o[r]);
            }
        }
    }
}

// ---------------------------------------------------------------- launcher
extern "C" void kernel_launch(void* const* d_in, const int* in_sizes, int n_in,
                              void* d_out, int out_size, void* d_ws, size_t ws_size,
                              hipStream_t stream) {
    const float* x      = (const float*)d_in[0];
    const float* a_w1   = (const float*)d_in[1];
    const float* a_b1   = (const float*)d_in[2];
    const float* a_w2   = (const float*)d_in[3];
    const float* a_b2   = (const float*)d_in[4];
    const float* qkv_w  = (const float*)d_in[5];
    const float* qkv_b  = (const float*)d_in[6];
    const float* proj_w = (const float*)d_in[7];
    const float* proj_b = (const float*)d_in[8];
    float* out = (float*)d_out;
    char* ws = (char*)d_ws;

    // ws layout (bytes, all 16B-aligned). Peak usage = 109,019,136 + 58,097,664 B ~= 104 MiB.
    // aout ALIASES xb: xb is dead after gemm<0>; attn rewrites rows 0..12607, and xb's
    // zero-filled pad rows (12608..12671) double as aout's pad rows for gemm<3>.
    u16* xb   = (u16*)(ws + 0);          // [12672][768]  bf16
    u16* xa   = (u16*)(ws + 19464192);   // [12672][768]  bf16
    u16* hbuf = (u16*)(ws + 38928384);   // [12672][256]  bf16
    u16* w1t  = (u16*)(ws + 45416448);   // [256][768]    bf16
    u16* w2t  = (u16*)(ws + 45809664);   // [768][256]    bf16
    u16* qwt  = (u16*)(ws + 46202880);   // [2304][768]   bf16
    u16* pwt  = (u16*)(ws + 49741824);   // [768][768]    bf16
    u16* qkv  = (u16*)(ws + 50921472);   // [3][64][12][197][64] bf16
    u16* aout = xb;                      // [12672][768]  bf16 (alias; see above)

    cast_x_kernel<<<4752, 256, 0, stream>>>(x, xb);
    transpose_cast_kernel<<<dim3(12, 4),  256, 0, stream>>>(a_w1,   w1t, 768, 192,  768);
    transpose_cast_kernel<<<dim3(4, 12),  256, 0, stream>>>(a_w2,   w2t, 192, 768,  256);
    transpose_cast_kernel<<<dim3(12, 36), 256, 0, stream>>>(qkv_w,  qwt, 768, 2304, 768);
    transpose_cast_kernel<<<dim3(12, 12), 256, 0, stream>>>(proj_w, pwt, 768, 768,  768);

    gemm_kernel<0><<<dim3(99, 2),  256, 0, stream>>>(xb,   w1t, a_b1,   nullptr, hbuf, nullptr, 768);
    gemm_kernel<1><<<dim3(99, 6),  256, 0, stream>>>(hbuf, w2t, a_b2,   x,       xa,   nullptr, 256);
    gemm_kernel<2><<<dim3(99, 18), 256, 0, stream>>>(xa,   qwt, qkv_b,  nullptr, qkv,  nullptr, 768);
    attn_kernel<<<NBT * NH, 256, 0, stream>>>(qkv, qkv + QKVSZ, qkv + 2 * (long)QKVSZ, aout);
    gemm_kernel<3><<<dim3(99, 6),  256, 0, stream>>>(aout, pwt, proj_b, nullptr, nullptr, out, 768);
}

// Round 3
// 369.696 us; speedup vs baseline: 1.0168x; 1.0168x over previous
//
#include <hip/hip_runtime.h>
#include <hip/hip_bf16.h>

typedef unsigned short u16;
typedef __attribute__((ext_vector_type(8))) short bf16x8;
typedef __attribute__((ext_vector_type(8))) unsigned short u16x8;
typedef __attribute__((ext_vector_type(4))) float f32x4;

#define NBT 64
#define SEQ 197
#define CDIM 768
#define NH 12
#define HD 64
#define MVALID (NBT * SEQ)       // 12608
#define MPAD 12672               // 99 * 128
#define HADP 192
#define HPAD 256
#define QKVSZ (NBT * NH * SEQ * HD)  // 9682944 elements

__device__ __forceinline__ u16 f2b(float f) {
    __hip_bfloat16 h = __float2bfloat16(f);
    return __builtin_bit_cast(u16, h);
}

#define GLL16(gp, lp) __builtin_amdgcn_global_load_lds( \
    (__attribute__((address_space(1))) void*)(gp),      \
    (__attribute__((address_space(3))) void*)(lp), 16, 0, 0)

// ---------------------------------------------------------------- cast x -> bf16, pad rows to MPAD with zeros
__global__ __launch_bounds__(256) void cast_x_kernel(const float* __restrict__ x, u16* __restrict__ xb) {
    long i = ((long)blockIdx.x * 256 + threadIdx.x) * 8;
    u16x8 r;
    if (i < (long)MVALID * CDIM) {
        const float4* p = (const float4*)(x + i);
        float4 a = p[0], b = p[1];
        r[0] = f2b(a.x); r[1] = f2b(a.y); r[2] = f2b(a.z); r[3] = f2b(a.w);
        r[4] = f2b(b.x); r[5] = f2b(b.y); r[6] = f2b(b.z); r[7] = f2b(b.w);
    } else {
#pragma unroll
        for (int j = 0; j < 8; ++j) r[j] = 0;
    }
    *(u16x8*)(xb + i) = r;
}

// ---------------------------------------------------------------- fp32 [K][N] -> bf16 [NP][KP] transpose+cast, zero pad
// grid = (KP/64, NP/64)
__global__ __launch_bounds__(256) void transpose_cast_kernel(
    const float* __restrict__ in, u16* __restrict__ out, int K, int N, int KP) {
    __shared__ float tile[64][65];
    int k0 = blockIdx.x * 64;
    int n0 = blockIdx.y * 64;
    int c  = threadIdx.x & 63;
    int r0 = threadIdx.x >> 6;
#pragma unroll
    for (int rr = r0; rr < 64; rr += 4) {
        int k = k0 + rr, n = n0 + c;
        tile[rr][c] = (k < K && n < N) ? in[(long)k * N + n] : 0.f;
    }
    __syncthreads();
#pragma unroll
    for (int rr = r0; rr < 64; rr += 4) {
        out[(long)(n0 + rr) * KP + k0 + c] = f2b(tile[c][rr]);
    }
}

// ---------------------------------------------------------------- GEMM: C[M,N] = A[M,K] * Bt[N,K]^T (+epilogue)
// 128x128 tile, BK=64, 256 threads (4 waves 2x2), dbuf LDS via global_load_lds w16.
// 1D grid of 99*NB blocks, XCD-swizzled (T1, bijective m204 form): each XCD owns a
// contiguous chunk of the flat (m-major, n-fastest) tile space, so its 4MB L2 holds
// {active A panel 196KB + full B panel} and A is fetched ~once chip-wide.
// MODE 0: h = acc + b1(pad0)            -> ob [MPAD][HPAD] bf16
// MODE 1: xa = acc + b2 + x (residual)  -> ob [MPAD][CDIM] bf16 (0 for pad rows)
// MODE 2: qkv scatter                   -> ob [3][NBT][NH][SEQ][HD] bf16
// MODE 3: out = acc + proj_b            -> of [MVALID][CDIM] fp32
template <int MODE, int NB>
__global__ __launch_bounds__(256, 2) void gemm_kernel(
    const u16* __restrict__ A, const u16* __restrict__ Bt,
    const float* __restrict__ bias, const float* __restrict__ resid,
    u16* __restrict__ ob, float* __restrict__ of, int K) {
    __shared__ __align__(16) u16 As[2][128 * 64];
    __shared__ __align__(16) u16 Bs[2][128 * 64];
    const int tid  = threadIdx.x;
    const int lane = tid & 63;
    const int w    = tid >> 6;
    const int wm   = w >> 1, wn = w & 1;

    // XCD-aware bijective swizzle (m204): bid%8 = XCD; each XCD gets a contiguous
    // wgid range of the flat m-major/n-fast tile index.
    const int nwg  = (int)gridDim.x;
    const int bid  = (int)blockIdx.x;
    const int q    = nwg >> 3, r = nwg & 7;
    const int xcd  = bid & 7;
    const int lid  = bid >> 3;
    const int wgid = (xcd < r ? xcd * (q + 1) : r * (q + 1) + (xcd - r) * q) + lid;
    const long m0  = (long)(wgid / NB) * 128;
    const long n0  = (long)(wgid % NB) * 128;

    const int rA = lane >> 3;
    const int cA = (lane & 7) * 8;

    const u16* ga[4];
    const u16* gb[4];
#pragma unroll
    for (int ii = 0; ii < 4; ++ii) {
        int i = w * 4 + ii;
        ga[ii] = A  + (m0 + i * 8 + rA) * K + cA;
        gb[ii] = Bt + (n0 + i * 8 + rA) * K + cA;
    }
#pragma unroll
    for (int ii = 0; ii < 4; ++ii) {
        int i = w * 4 + ii;
        GLL16(ga[ii], &As[0][i * 512]);
        GLL16(gb[ii], &Bs[0][i * 512]);
    }

    int aoff[4], boff[4];
#pragma unroll
    for (int t = 0; t < 4; ++t) {
        aoff[t] = (wm * 64 + t * 16 + (lane & 15)) * 64 + (lane >> 4) * 8;
        boff[t] = (wn * 64 + t * 16 + (lane & 15)) * 64 + (lane >> 4) * 8;
    }

    f32x4 acc[4][4] = {};
    const int kSteps = K >> 6;
    __syncthreads();
    int buf = 0;
    for (int kt = 0; kt < kSteps; ++kt) {
        if (kt + 1 < kSteps) {
#pragma unroll
            for (int ii = 0; ii < 4; ++ii) {
                int i = w * 4 + ii;
                GLL16(ga[ii] + (kt + 1) * 64, &As[buf ^ 1][i * 512]);
                GLL16(gb[ii] + (kt + 1) * 64, &Bs[buf ^ 1][i * 512]);
            }
        }
#pragma unroll
        for (int kc = 0; kc < 2; ++kc) {
            bf16x8 af[4], bg[4];
#pragma unroll
            for (int t = 0; t < 4; ++t) af[t] = *(const bf16x8*)&As[buf][aoff[t] + kc * 32];
#pragma unroll
            for (int t = 0; t < 4; ++t) bg[t] = *(const bf16x8*)&Bs[buf][boff[t] + kc * 32];
#pragma unroll
            for (int mi = 0; mi < 4; ++mi)
#pragma unroll
                for (int ni = 0; ni < 4; ++ni)
                    acc[mi][ni] = __builtin_amdgcn_mfma_f32_16x16x32_bf16(af[mi], bg[ni], acc[mi][ni], 0, 0, 0);
        }
        __syncthreads();
        buf ^= 1;
    }

    // epilogue: D row = (lane>>4)*4 + r, col = lane&15 within each 16x16 frag
    const int rb = (lane >> 4) * 4;
    const int cl = lane & 15;
#pragma unroll
    for (int mi = 0; mi < 4; ++mi) {
#pragma unroll
        for (int rr = 0; rr < 4; ++rr) {
            long m = m0 + wm * 64 + mi * 16 + rb + rr;
#pragma unroll
            for (int ni = 0; ni < 4; ++ni) {
                long n = n0 + wn * 64 + ni * 16 + cl;
                float v = acc[mi][ni][rr];
                if constexpr (MODE == 0) {
                    float bv = (n < HADP) ? bias[n] : 0.f;
                    ob[m * HPAD + n] = f2b(v + bv);
                } else if constexpr (MODE == 1) {
                    float val = 0.f;
                    if (m < MVALID) val = v + bias[n] + resid[m * CDIM + n];
                    ob[m * CDIM + n] = f2b(val);
                } else if constexpr (MODE == 2) {
                    if (m < MVALID) {
                        int mm = (int)m;
                        int bb = mm / SEQ;
                        int t  = mm - bb * SEQ;
                        int nn = (int)n;
                        int which = nn / CDIM;
                        int c  = nn - which * CDIM;
                        int hh = c >> 6, d = c & 63;
                        ob[(long)which * QKVSZ + ((long)(bb * NH + hh) * SEQ + t) * HD + d] = f2b(v + bias[nn]);
                    }
                } else {
                    if (m < MVALID) of[m * CDIM + n] = v + bias[n];
                }
            }
        }
    }
}

// ---------------------------------------------------------------- attention: one block per (b,h), 4 waves
// Head reallocation handled by reading K/V from bsrc (shifted frame).
__global__ __launch_bounds__(256, 2) void attn_kernel(
    const u16* __restrict__ qb, const u16* __restrict__ kb, const u16* __restrict__ vb,
    u16* __restrict__ aout) {
    __shared__ __align__(16) u16 Vt[64 * 232];        // V transposed [d][token], padded
    __shared__ __align__(16) u16 P[4][16 * 232];      // per-wave P tile
    const int bid = blockIdx.x;
    const int b = bid / NH;
    const int h = bid - b * NH;
    const int f = b & 7;
    int fs = (h < 2) ? (f > 0 ? f - 1 : 0) : ((h < 4) ? (f < 7 ? f + 1 : 7) : f);
    const int bsrc = (b & ~7) + fs;
    const u16* Qp = qb + (long)(b    * NH + h) * SEQ * HD;
    const u16* Kp = kb + (long)(bsrc * NH + h) * SEQ * HD;
    const u16* Vp = vb + (long)(bsrc * NH + h) * SEQ * HD;

    const int tid  = threadIdx.x;
    const int lane = tid & 63;
    const int w    = tid >> 6;
    const int cl   = lane & 15;
    const int lg   = lane >> 4;

    {   // zero Vt and P (pad columns must be exactly 0)
        unsigned int* z1 = (unsigned int*)Vt;
        for (int i = tid; i < 64 * 232 / 2; i += 256) z1[i] = 0;
        unsigned int* z2 = (unsigned int*)&P[0][0];
        for (int i = tid; i < 4 * 16 * 232 / 2; i += 256) z2[i] = 0;
    }
    __syncthreads();
    for (int g = tid; g < SEQ * HD / 8; g += 256) {   // transpose-stage V
        int t  = g >> 3;
        int d0 = (g & 7) * 8;
        u16x8 v = *(const u16x8*)(Vp + g * 8);
#pragma unroll
        for (int j = 0; j < 8; ++j) Vt[(d0 + j) * 232 + t] = v[j];
    }
    __syncthreads();

    const f32x4 vzero = {0.f, 0.f, 0.f, 0.f};
    u16* Pw = &P[w][0];
    for (int rt = w; rt < 13; rt += 4) {
        int qrow = rt * 16 + cl; if (qrow > SEQ - 1) qrow = SEQ - 1;
        bf16x8 qf0 = *(const bf16x8*)(Qp + qrow * HD + lg * 8);
        bf16x8 qf1 = *(const bf16x8*)(Qp + qrow * HD + 32 + lg * 8);
        f32x4 s[13];
#pragma unroll
        for (int ct = 0; ct < 13; ++ct) s[ct] = vzero;
#pragma unroll
        for (int ct = 0; ct < 13; ++ct) {
            int krow = ct * 16 + cl; if (krow > SEQ - 1) krow = SEQ - 1;
            bf16x8 kf0 = *(const bf16x8*)(Kp + krow * HD + lg * 8);
            bf16x8 kf1 = *(const bf16x8*)(Kp + krow * HD + 32 + lg * 8);
            s[ct] = __builtin_amdgcn_mfma_f32_16x16x32_bf16(qf0, kf0, s[ct], 0, 0, 0);
            s[ct] = __builtin_amdgcn_mfma_f32_16x16x32_bf16(qf1, kf1, s[ct], 0, 0, 0);
        }
        // scale + mask + row max (rows lg*4..lg*4+3 live in 16-lane group lg)
        float rm[4] = {-1e30f, -1e30f, -1e30f, -1e30f};
#pragma unroll
        for (int ct = 0; ct < 13; ++ct) {
            bool valid = (ct * 16 + cl) <= SEQ - 1;
#pragma unroll
            for (int r = 0; r < 4; ++r) {
                float v = valid ? s[ct][r] * 0.125f : -1e30f;
                s[ct][r] = v;
                rm[r] = fmaxf(rm[r], v);
            }
        }
#pragma unroll
        for (int off = 1; off <= 8; off <<= 1)
#pragma unroll
            for (int r = 0; r < 4; ++r) rm[r] = fmaxf(rm[r], __shfl_xor(rm[r], off));
        float rs[4] = {0.f, 0.f, 0.f, 0.f};
#pragma unroll
        for (int ct = 0; ct < 13; ++ct)
#pragma unroll
            for (int r = 0; r < 4; ++r) {
                float p = __expf(s[ct][r] - rm[r]);
                s[ct][r] = p;
                rs[r] += p;
            }
#pragma unroll
        for (int off = 1; off <= 8; off <<= 1)
#pragma unroll
            for (int r = 0; r < 4; ++r) rs[r] += __shfl_xor(rs[r], off);
        float inv[4];
#pragma unroll
        for (int r = 0; r < 4; ++r) inv[r] = 1.f / rs[r];

        // write normalized P (bf16) to per-wave LDS; order DS ops around the cross-lane handoff
        asm volatile("s_waitcnt lgkmcnt(0)" ::: "memory");
#pragma unroll
        for (int ct = 0; ct < 13; ++ct)
#pragma unroll
            for (int r = 0; r < 4; ++r)
                Pw[(lg * 4 + r) * 232 + ct * 16 + cl] = f2b(s[ct][r] * inv[r]);
        asm volatile("s_waitcnt lgkmcnt(0)" ::: "memory");

        bf16x8 pf[7];
#pragma unroll
        for (int ks = 0; ks < 7; ++ks)
            pf[ks] = *(const bf16x8*)(Pw + cl * 232 + ks * 32 + lg * 8);
#pragma unroll
        for (int dt = 0; dt < 4; ++dt) {
            f32x4 o = vzero;
#pragma unroll
            for (int ks = 0; ks < 7; ++ks) {
                bf16x8 vf = *(const bf16x8*)(&Vt[(dt * 16 + cl) * 232 + ks * 32 + lg * 8]);
                o = __builtin_amdgcn_mfma_f32_16x16x32_bf16(pf[ks], vf, o, 0, 0, 0);
            }
#pragma unroll
            for (int r = 0; r < 4; ++r) {
                int m = rt * 16 + lg * 4 + r;
                if (m < SEQ)
                    aout[(long)(b * SEQ + m) * CDIM + h * HD + dt * 16 + cl] = f2b(o[r]);
            }
        }
    }
}

// ---------------------------------------------------------------- launcher
extern "C" void kernel_launch(void* const* d_in, const int* in_sizes, int n_in,
                              void* d_out, int out_size, void* d_ws, size_t ws_size,
                              hipStream_t stream) {
    const float* x      = (const float*)d_in[0];
    const float* a_w1   = (const float*)d_in[1];
    const float* a_b1   = (const float*)d_in[2];
    const float* a_w2   = (const float*)d_in[3];
    const float* a_b2   = (const float*)d_in[4];
    const float* qkv_w  = (const float*)d_in[5];
    const float* qkv_b  = (const float*)d_in[6];
    const float* proj_w = (const float*)d_in[7];
    const float* proj_b = (const float*)d_in[8];
    float* out = (float*)d_out;
    char* ws = (char*)d_ws;

    // ws layout (bytes, all 16B-aligned). Peak usage ~= 104 MiB.
    // aout ALIASES xb: xb is dead after gemm<0>; attn rewrites rows 0..12607, and xb's
    // zero-filled pad rows (12608..12671) double as aout's pad rows for gemm<3>.
    u16* xb   = (u16*)(ws + 0);          // [12672][768]  bf16
    u16* xa   = (u16*)(ws + 19464192);   // [12672][768]  bf16
    u16* hbuf = (u16*)(ws + 38928384);   // [12672][256]  bf16
    u16* w1t  = (u16*)(ws + 45416448);   // [256][768]    bf16
    u16* w2t  = (u16*)(ws + 45809664);   // [768][256]    bf16
    u16* qwt  = (u16*)(ws + 46202880);   // [2304][768]   bf16
    u16* pwt  = (u16*)(ws + 49741824);   // [768][768]    bf16
    u16* qkv  = (u16*)(ws + 50921472);   // [3][64][12][197][64] bf16
    u16* aout = xb;                      // [12672][768]  bf16 (alias; see above)

    cast_x_kernel<<<4752, 256, 0, stream>>>(x, xb);
    transpose_cast_kernel<<<dim3(12, 4),  256, 0, stream>>>(a_w1,   w1t, 768, 192,  768);
    transpose_cast_kernel<<<dim3(4, 12),  256, 0, stream>>>(a_w2,   w2t, 192, 768,  256);
    transpose_cast_kernel<<<dim3(12, 36), 256, 0, stream>>>(qkv_w,  qwt, 768, 2304, 768);
    transpose_cast_kernel<<<dim3(12, 12), 256, 0, stream>>>(proj_w, pwt, 768, 768,  768);

    gemm_kernel<0, 2><<<99 * 2,  256, 0, stream>>>(xb,   w1t, a_b1,   nullptr, hbuf, nullptr, 768);
    gemm_kernel<1, 6><<<99 * 6,  256, 0, stream>>>(hbuf, w2t, a_b2,   x,       xa,   nullptr, 256);
    gemm_kernel<2, 18><<<99 * 18, 256, 0, stream>>>(xa,   qwt, qkv_b,  nullptr, qkv,  nullptr, 768);
    attn_kernel<<<NBT * NH, 256, 0, stream>>>(qkv, qkv + QKVSZ, qkv + 2 * (long)QKVSZ, aout);
    gemm_kernel<3, 6><<<99 * 6,  256, 0, stream>>>(aout, pwt, proj_b, nullptr, nullptr, out, 768);
}

// Round 4
// 310.998 us; speedup vs baseline: 1.2087x; 1.1887x over previous
//
#include <hip/hip_runtime.h>
#include <hip/hip_bf16.h>

typedef unsigned short u16;
typedef __attribute__((ext_vector_type(8))) short bf16x8;
typedef __attribute__((ext_vector_type(8))) unsigned short u16x8;
typedef __attribute__((ext_vector_type(4))) float f32x4;

#define NBT 64
#define SEQ 197
#define CDIM 768
#define NH 12
#define HD 64
#define MVALID (NBT * SEQ)       // 12608
#define MPAD 12672               // 99 * 128
#define HADP 192
#define HPAD 256
#define QKVSZ (NBT * NH * SEQ * HD)  // 9682944 elements

__device__ __forceinline__ u16 f2b(float f) {
    __hip_bfloat16 h = __float2bfloat16(f);
    return __builtin_bit_cast(u16, h);
}

#define GLL16(gp, lp) __builtin_amdgcn_global_load_lds( \
    (__attribute__((address_space(1))) void*)(gp),      \
    (__attribute__((address_space(3))) void*)(lp), 16, 0, 0)

// ---------------------------------------------------------------- cast x -> bf16, pad rows to MPAD with zeros
__global__ __launch_bounds__(256) void cast_x_kernel(const float* __restrict__ x, u16* __restrict__ xb) {
    long i = ((long)blockIdx.x * 256 + threadIdx.x) * 8;
    u16x8 r;
    if (i < (long)MVALID * CDIM) {
        const float4* p = (const float4*)(x + i);
        float4 a = p[0], b = p[1];
        r[0] = f2b(a.x); r[1] = f2b(a.y); r[2] = f2b(a.z); r[3] = f2b(a.w);
        r[4] = f2b(b.x); r[5] = f2b(b.y); r[6] = f2b(b.z); r[7] = f2b(b.w);
    } else {
#pragma unroll
        for (int j = 0; j < 8; ++j) r[j] = 0;
    }
    *(u16x8*)(xb + i) = r;
}

// ---------------------------------------------------------------- fp32 [K][N] -> bf16 [NP][KP] transpose+cast, zero pad
// grid = (KP/64, NP/64)
__global__ __launch_bounds__(256) void transpose_cast_kernel(
    const float* __restrict__ in, u16* __restrict__ out, int K, int N, int KP) {
    __shared__ float tile[64][65];
    int k0 = blockIdx.x * 64;
    int n0 = blockIdx.y * 64;
    int c  = threadIdx.x & 63;
    int r0 = threadIdx.x >> 6;
#pragma unroll
    for (int rr = r0; rr < 64; rr += 4) {
        int k = k0 + rr, n = n0 + c;
        tile[rr][c] = (k < K && n < N) ? in[(long)k * N + n] : 0.f;
    }
    __syncthreads();
#pragma unroll
    for (int rr = r0; rr < 64; rr += 4) {
        out[(long)(n0 + rr) * KP + k0 + c] = f2b(tile[c][rr]);
    }
}

// ---------------------------------------------------------------- GEMM body: C[M,N] = A[M,K] * Bt[N,K]^T (+epilogue)
// m97 structure: 128x128 tile, BK=64, 4 waves (2x2), SINGLE-buffer 32KB LDS,
// 2 barriers per K-step, global_load_lds w16, 4-5 blocks/CU for implicit
// wave-level pipeline (m99/m100: explicit dbuf is not better; occupancy is).
// T1 XCD swizzle (bijective m204): flat tile id m-major/n-fastest, contiguous
// chunk per XCD so A-panel + B-panel stay in that XCD's 4MB L2.
// MODE 0: h = acc + b1(pad0)            -> ob [MPAD][HPAD] bf16
// MODE 1: xa = acc + b2 + x (residual)  -> ob [MPAD][CDIM] bf16 (0 for pad rows)
// MODE 2: qkv scatter                   -> ob [3][NBT][NH][SEQ][HD] bf16
// MODE 3: out = acc + proj_b            -> of [MVALID][CDIM] fp32
template <int MODE, int NB>
__device__ __forceinline__ void gemm_body(
    const u16* __restrict__ A, const u16* __restrict__ Bt,
    const float* __restrict__ bias, const float* __restrict__ resid,
    u16* __restrict__ ob, float* __restrict__ of, int K) {
    __shared__ __align__(16) u16 As[128 * 64];
    __shared__ __align__(16) u16 Bs[128 * 64];
    const int tid  = threadIdx.x;
    const int lane = tid & 63;
    const int w    = tid >> 6;
    const int wm   = w >> 1, wn = w & 1;

    const int nwg  = (int)gridDim.x;
    const int bid  = (int)blockIdx.x;
    const int q    = nwg >> 3, r = nwg & 7;
    const int xcd  = bid & 7;
    const int lid  = bid >> 3;
    const int wgid = (xcd < r ? xcd * (q + 1) : r * (q + 1) + (xcd - r) * q) + lid;
    const long m0  = (long)(wgid / NB) * 128;
    const long n0  = (long)(wgid % NB) * 128;

    const int rA = lane >> 3;
    const int cA = (lane & 7) * 8;

    const u16* ga[4];
    const u16* gb[4];
#pragma unroll
    for (int ii = 0; ii < 4; ++ii) {
        int i = w * 4 + ii;
        ga[ii] = A  + (m0 + i * 8 + rA) * K + cA;
        gb[ii] = Bt + (n0 + i * 8 + rA) * K + cA;
    }

    int aoff[4], boff[4];
#pragma unroll
    for (int t = 0; t < 4; ++t) {
        aoff[t] = (wm * 64 + t * 16 + (lane & 15)) * 64 + (lane >> 4) * 8;
        boff[t] = (wn * 64 + t * 16 + (lane & 15)) * 64 + (lane >> 4) * 8;
    }

    f32x4 acc[4][4] = {};
    const int kSteps = K >> 6;
    for (int kt = 0; kt < kSteps; ++kt) {
#pragma unroll
        for (int ii = 0; ii < 4; ++ii) {
            int i = w * 4 + ii;
            GLL16(ga[ii] + kt * 64, &As[i * 512]);
            GLL16(gb[ii] + kt * 64, &Bs[i * 512]);
        }
        __syncthreads();   // compiler drains vmcnt before s_barrier -> tile resident
#pragma unroll
        for (int kc = 0; kc < 2; ++kc) {
            bf16x8 af[4], bg[4];
#pragma unroll
            for (int t = 0; t < 4; ++t) af[t] = *(const bf16x8*)&As[aoff[t] + kc * 32];
#pragma unroll
            for (int t = 0; t < 4; ++t) bg[t] = *(const bf16x8*)&Bs[boff[t] + kc * 32];
#pragma unroll
            for (int mi = 0; mi < 4; ++mi)
#pragma unroll
                for (int ni = 0; ni < 4; ++ni)
                    acc[mi][ni] = __builtin_amdgcn_mfma_f32_16x16x32_bf16(af[mi], bg[ni], acc[mi][ni], 0, 0, 0);
        }
        __syncthreads();   // all waves done reading LDS before next GLL overwrites
    }

    // epilogue: D row = (lane>>4)*4 + r, col = lane&15 within each 16x16 frag
    const int rb = (lane >> 4) * 4;
    const int cl = lane & 15;
#pragma unroll
    for (int mi = 0; mi < 4; ++mi) {
#pragma unroll
        for (int rr = 0; rr < 4; ++rr) {
            long m = m0 + wm * 64 + mi * 16 + rb + rr;
#pragma unroll
            for (int ni = 0; ni < 4; ++ni) {
                long n = n0 + wn * 64 + ni * 16 + cl;
                float v = acc[mi][ni][rr];
                if constexpr (MODE == 0) {
                    float bv = (n < HADP) ? bias[n] : 0.f;
                    ob[m * HPAD + n] = f2b(v + bv);
                } else if constexpr (MODE == 1) {
                    float val = 0.f;
                    if (m < MVALID) val = v + bias[n] + resid[m * CDIM + n];
                    ob[m * CDIM + n] = f2b(val);
                } else if constexpr (MODE == 2) {
                    if (m < MVALID) {
                        int mm = (int)m;
                        int bb = mm / SEQ;
                        int t  = mm - bb * SEQ;
                        int nn = (int)n;
                        int which = nn / CDIM;
                        int c  = nn - which * CDIM;
                        int hh = c >> 6, d = c & 63;
                        ob[(long)which * QKVSZ + ((long)(bb * NH + hh) * SEQ + t) * HD + d] = f2b(v + bias[nn]);
                    }
                } else {
                    if (m < MVALID) of[m * CDIM + n] = v + bias[n];
                }
            }
        }
    }
}

// Distinct symbols per mode so rocprof's top-k decomposes the pipeline.
__global__ __launch_bounds__(256, 4) void gemm_a1(
    const u16* __restrict__ A, const u16* __restrict__ Bt, const float* __restrict__ bias,
    u16* __restrict__ ob, int K) {
    gemm_body<0, 2>(A, Bt, bias, nullptr, ob, nullptr, K);
}
__global__ __launch_bounds__(256, 4) void gemm_a2(
    const u16* __restrict__ A, const u16* __restrict__ Bt, const float* __restrict__ bias,
    const float* __restrict__ resid, u16* __restrict__ ob, int K) {
    gemm_body<1, 6>(A, Bt, bias, resid, ob, nullptr, K);
}
__global__ __launch_bounds__(256, 4) void gemm_qkv(
    const u16* __restrict__ A, const u16* __restrict__ Bt, const float* __restrict__ bias,
    u16* __restrict__ ob, int K) {
    gemm_body<2, 18>(A, Bt, bias, nullptr, ob, nullptr, K);
}
__global__ __launch_bounds__(256, 4) void gemm_proj(
    const u16* __restrict__ A, const u16* __restrict__ Bt, const float* __restrict__ bias,
    float* __restrict__ of, int K) {
    gemm_body<3, 6>(A, Bt, bias, nullptr, nullptr, of, K);
}

// ---------------------------------------------------------------- attention: one block per (b,h), 4 waves
// Head reallocation handled by reading K/V from bsrc (shifted frame).
__global__ __launch_bounds__(256, 2) void attn_kernel(
    const u16* __restrict__ qb, const u16* __restrict__ kb, const u16* __restrict__ vb,
    u16* __restrict__ aout) {
    __shared__ __align__(16) u16 Vt[64 * 232];        // V transposed [d][token], padded
    __shared__ __align__(16) u16 P[4][16 * 232];      // per-wave P tile
    const int bid = blockIdx.x;
    const int b = bid / NH;
    const int h = bid - b * NH;
    const int f = b & 7;
    int fs = (h < 2) ? (f > 0 ? f - 1 : 0) : ((h < 4) ? (f < 7 ? f + 1 : 7) : f);
    const int bsrc = (b & ~7) + fs;
    const u16* Qp = qb + (long)(b    * NH + h) * SEQ * HD;
    const u16* Kp = kb + (long)(bsrc * NH + h) * SEQ * HD;
    const u16* Vp = vb + (long)(bsrc * NH + h) * SEQ * HD;

    const int tid  = threadIdx.x;
    const int lane = tid & 63;
    const int w    = tid >> 6;
    const int cl   = lane & 15;
    const int lg   = lane >> 4;

    {   // zero Vt and P (pad columns must be exactly 0)
        unsigned int* z1 = (unsigned int*)Vt;
        for (int i = tid; i < 64 * 232 / 2; i += 256) z1[i] = 0;
        unsigned int* z2 = (unsigned int*)&P[0][0];
        for (int i = tid; i < 4 * 16 * 232 / 2; i += 256) z2[i] = 0;
    }
    __syncthreads();
    for (int g = tid; g < SEQ * HD / 8; g += 256) {   // transpose-stage V
        int t  = g >> 3;
        int d0 = (g & 7) * 8;
        u16x8 v = *(const u16x8*)(Vp + g * 8);
#pragma unroll
        for (int j = 0; j < 8; ++j) Vt[(d0 + j) * 232 + t] = v[j];
    }
    __syncthreads();

    const f32x4 vzero = {0.f, 0.f, 0.f, 0.f};
    u16* Pw = &P[w][0];
    for (int rt = w; rt < 13; rt += 4) {
        int qrow = rt * 16 + cl; if (qrow > SEQ - 1) qrow = SEQ - 1;
        bf16x8 qf0 = *(const bf16x8*)(Qp + qrow * HD + lg * 8);
        bf16x8 qf1 = *(const bf16x8*)(Qp + qrow * HD + 32 + lg * 8);
        f32x4 s[13];
#pragma unroll
        for (int ct = 0; ct < 13; ++ct) s[ct] = vzero;
#pragma unroll
        for (int ct = 0; ct < 13; ++ct) {
            int krow = ct * 16 + cl; if (krow > SEQ - 1) krow = SEQ - 1;
            bf16x8 kf0 = *(const bf16x8*)(Kp + krow * HD + lg * 8);
            bf16x8 kf1 = *(const bf16x8*)(Kp + krow * HD + 32 + lg * 8);
            s[ct] = __builtin_amdgcn_mfma_f32_16x16x32_bf16(qf0, kf0, s[ct], 0, 0, 0);
            s[ct] = __builtin_amdgcn_mfma_f32_16x16x32_bf16(qf1, kf1, s[ct], 0, 0, 0);
        }
        // scale + mask + row max (rows lg*4..lg*4+3 live in 16-lane group lg)
        float rm[4] = {-1e30f, -1e30f, -1e30f, -1e30f};
#pragma unroll
        for (int ct = 0; ct < 13; ++ct) {
            bool valid = (ct * 16 + cl) <= SEQ - 1;
#pragma unroll
            for (int r = 0; r < 4; ++r) {
                float v = valid ? s[ct][r] * 0.125f : -1e30f;
                s[ct][r] = v;
                rm[r] = fmaxf(rm[r], v);
            }
        }
#pragma unroll
        for (int off = 1; off <= 8; off <<= 1)
#pragma unroll
            for (int r = 0; r < 4; ++r) rm[r] = fmaxf(rm[r], __shfl_xor(rm[r], off));
        float rs[4] = {0.f, 0.f, 0.f, 0.f};
#pragma unroll
        for (int ct = 0; ct < 13; ++ct)
#pragma unroll
            for (int r = 0; r < 4; ++r) {
                float p = __expf(s[ct][r] - rm[r]);
                s[ct][r] = p;
                rs[r] += p;
            }
#pragma unroll
        for (int off = 1; off <= 8; off <<= 1)
#pragma unroll
            for (int r = 0; r < 4; ++r) rs[r] += __shfl_xor(rs[r], off);
        float inv[4];
#pragma unroll
        for (int r = 0; r < 4; ++r) inv[r] = 1.f / rs[r];

        // write normalized P (bf16) to per-wave LDS; order DS ops around the cross-lane handoff
        asm volatile("s_waitcnt lgkmcnt(0)" ::: "memory");
#pragma unroll
        for (int ct = 0; ct < 13; ++ct)
#pragma unroll
            for (int r = 0; r < 4; ++r)
                Pw[(lg * 4 + r) * 232 + ct * 16 + cl] = f2b(s[ct][r] * inv[r]);
        asm volatile("s_waitcnt lgkmcnt(0)" ::: "memory");

        bf16x8 pf[7];
#pragma unroll
        for (int ks = 0; ks < 7; ++ks)
            pf[ks] = *(const bf16x8*)(Pw + cl * 232 + ks * 32 + lg * 8);
#pragma unroll
        for (int dt = 0; dt < 4; ++dt) {
            f32x4 o = vzero;
#pragma unroll
            for (int ks = 0; ks < 7; ++ks) {
                bf16x8 vf = *(const bf16x8*)(&Vt[(dt * 16 + cl) * 232 + ks * 32 + lg * 8]);
                o = __builtin_amdgcn_mfma_f32_16x16x32_bf16(pf[ks], vf, o, 0, 0, 0);
            }
#pragma unroll
            for (int r = 0; r < 4; ++r) {
                int m = rt * 16 + lg * 4 + r;
                if (m < SEQ)
                    aout[(long)(b * SEQ + m) * CDIM + h * HD + dt * 16 + cl] = f2b(o[r]);
            }
        }
    }
}

// ---------------------------------------------------------------- launcher
extern "C" void kernel_launch(void* const* d_in, const int* in_sizes, int n_in,
                              void* d_out, int out_size, void* d_ws, size_t ws_size,
                              hipStream_t stream) {
    const float* x      = (const float*)d_in[0];
    const float* a_w1   = (const float*)d_in[1];
    const float* a_b1   = (const float*)d_in[2];
    const float* a_w2   = (const float*)d_in[3];
    const float* a_b2   = (const float*)d_in[4];
    const float* qkv_w  = (const float*)d_in[5];
    const float* qkv_b  = (const float*)d_in[6];
    const float* proj_w = (const float*)d_in[7];
    const float* proj_b = (const float*)d_in[8];
    float* out = (float*)d_out;
    char* ws = (char*)d_ws;

    // ws layout (bytes, all 16B-aligned). Peak usage ~= 104 MiB.
    // aout ALIASES xb: xb is dead after gemm_a1; attn rewrites rows 0..12607, and xb's
    // zero-filled pad rows (12608..12671) double as aout's pad rows for gemm_proj.
    u16* xb   = (u16*)(ws + 0);          // [12672][768]  bf16
    u16* xa   = (u16*)(ws + 19464192);   // [12672][768]  bf16
    u16* hbuf = (u16*)(ws + 38928384);   // [12672][256]  bf16
    u16* w1t  = (u16*)(ws + 45416448);   // [256][768]    bf16
    u16* w2t  = (u16*)(ws + 45809664);   // [768][256]    bf16
    u16* qwt  = (u16*)(ws + 46202880);   // [2304][768]   bf16
    u16* pwt  = (u16*)(ws + 49741824);   // [768][768]    bf16
    u16* qkv  = (u16*)(ws + 50921472);   // [3][64][12][197][64] bf16
    u16* aout = xb;                      // [12672][768]  bf16 (alias; see above)

    cast_x_kernel<<<4752, 256, 0, stream>>>(x, xb);
    transpose_cast_kernel<<<dim3(12, 4),  256, 0, stream>>>(a_w1,   w1t, 768, 192,  768);
    transpose_cast_kernel<<<dim3(4, 12),  256, 0, stream>>>(a_w2,   w2t, 192, 768,  256);
    transpose_cast_kernel<<<dim3(12, 36), 256, 0, stream>>>(qkv_w,  qwt, 768, 2304, 768);
    transpose_cast_kernel<<<dim3(12, 12), 256, 0, stream>>>(proj_w, pwt, 768, 768,  768);

    gemm_a1  <<<99 * 2,  256, 0, stream>>>(xb,   w1t, a_b1,  hbuf, 768);
    gemm_a2  <<<99 * 6,  256, 0, stream>>>(hbuf, w2t, a_b2,  x, xa, 256);
    gemm_qkv <<<99 * 18, 256, 0, stream>>>(xa,   qwt, qkv_b, qkv,   768);
    attn_kernel<<<NBT * NH, 256, 0, stream>>>(qkv, qkv + QKVSZ, qkv + 2 * (long)QKVSZ, aout);
    gemm_proj<<<99 * 6,  256, 0, stream>>>(aout, pwt, proj_b, out,  768);
}